// Round 9
// baseline (296.668 us; speedup 1.0000x reference)
//
#include <hip/hip_runtime.h>
#include <math.h>

#define BT 8192      // B*T
#define NDIM 512     // INPUT_DIM
#define NFREQ 257
#define DDIM 128     // VQ_DIM
#define NEMBED 8192
#define NQ 4         // codebook slices
#define ROWS 32768   // BT*4 splits

typedef _Float16 half8 __attribute__((ext_vector_type(8)));
typedef float f32x4 __attribute__((ext_vector_type(4)));

#define SCALE_DN 2.44140625e-4f   // 2^-12

// ---------------- prep kernel: blocks [0,512) = codebook split; [512,640) = W build ----
// cb part: per 16-code tile, normalize + f16 hi/lo split, write B-fragment-ordered image.
// W part: rebuild K_s from cos LUT, window-conv vs proj, write W in B-FRAGMENT order:
//   Wimg half8 index = ((sIdx*16 + it)*8 + set)*64 + lg*16 + lr
//   holding W^T[c = sIdx*128+set*16+lr][k = it*32+lg*8 .. +8]
__global__ __launch_bounds__(256) void prep_kernel(const float* __restrict__ cb,
                                                   const float* __restrict__ proj,
                                                   const int* __restrict__ rm,
                                                   _Float16* __restrict__ chi,
                                                   _Float16* __restrict__ clo,
                                                   _Float16* __restrict__ Wth,
                                                   _Float16* __restrict__ Wtl) {
    int t = threadIdx.x;
    if (blockIdx.x < 512) {
        // ---- codebook split ----
        __shared__ float tile[16][132];
        __shared__ float rns[16];
        int tileIdx = blockIdx.x;
        int row = t >> 4, seg = t & 15;
        const float* src = cb + ((size_t)tileIdx * 16 + row) * DDIM + seg * 8;
        float4 v0 = *(const float4*)src;
        float4 v1 = *(const float4*)(src + 4);
        *(float4*)&tile[row][seg * 8] = v0;
        *(float4*)&tile[row][seg * 8 + 4] = v1;
        float ss = v0.x * v0.x;
        ss = fmaf(v0.y, v0.y, ss); ss = fmaf(v0.z, v0.z, ss); ss = fmaf(v0.w, v0.w, ss);
        ss = fmaf(v1.x, v1.x, ss); ss = fmaf(v1.y, v1.y, ss);
        ss = fmaf(v1.z, v1.z, ss); ss = fmaf(v1.w, v1.w, ss);
#pragma unroll
        for (int m = 1; m < 16; m <<= 1) ss += __shfl_xor(ss, m);
        if (seg == 0) rns[row] = 1.0f / sqrtf(ss);
        __syncthreads();
        int cr = t & 15, lgq = (t >> 4) & 3, kt = t >> 6;
        int k0 = kt * 32 + lgq * 8;
        float rn = rns[cr];
        half8 oh, ol;
#pragma unroll
        for (int j = 0; j < 8; ++j) {
            float f = tile[cr][k0 + j] * rn;
            _Float16 h = (_Float16)f;
            oh[j] = h;
            ol[j] = (_Float16)((f - (float)h) * 4096.0f);
        }
        size_t dst = (size_t)tileIdx * 2048 + t * 8;
        *(half8*)(chi + dst) = oh;
        *(half8*)(clo + dst) = ol;
    } else {
        // ---- W^T build + f16 split, fragment-ordered output ----
        __shared__ float ctab[512];
        __shared__ float Ks[512];
        __shared__ int rms[NFREQ];
        int bxp = blockIdx.x - 512;          // [0,128)
        int s = bxp & 3, ntp = bxp >> 2;     // s split, 16-k group
        int d = t & 127;
        int n0 = ntp * 16 + (t >> 7) * 8;
        for (int i = t; i < 512; i += 256) ctab[i] = cospif((float)i * (1.0f / 256.0f));
        for (int i = t; i < NFREQ; i += 256) rms[i] = rm[i];
        __syncthreads();
        for (int base = t; base < 512; base += 256) {
            float acc = 0.0f;
            for (int f = 0; f < NFREQ; ++f) {
                float w = (f == 0 || f == 256) ? 1.0f : 2.0f;
                float c = w * ctab[(f * base) & 511];
                acc += (rms[f] == s) ? c : 0.0f;
            }
            Ks[base] = acc * (1.0f / 512.0f);
        }
        __syncthreads();
        float acc[8] = {};
        for (int p16 = 0; p16 < 512; p16 += 16) {
            float wv[23];
#pragma unroll
            for (int j2 = 0; j2 < 23; ++j2) wv[j2] = Ks[(p16 - n0 + j2 - 7) & 511];
#pragma unroll
            for (int j = 0; j < 16; ++j) {
                float xp = proj[(p16 + j) * DDIM + d];
#pragma unroll
                for (int i = 0; i < 8; ++i)
                    acc[i] = fmaf(xp, wv[7 + j - i], acc[i]);
            }
        }
        // fragment-image store
        int set = d >> 4, lr = d & 15;
        int itk = n0 >> 5, lg = (n0 >> 3) & 3;
        size_t idx8 = ((size_t)((s * 16 + itk) * 8 + set)) * 64 + lg * 16 + lr;
        half8 oh, ol;
#pragma unroll
        for (int i = 0; i < 8; ++i) {
            float f = acc[i] * 256.0f;      // pre-scale: dodge f16 denormals (norm cancels)
            _Float16 h = (_Float16)f;
            oh[i] = h;
            ol[i] = (_Float16)((f - (float)h) * 4096.0f);
        }
        *(half8*)(Wth + idx8 * 8) = oh;
        *(half8*)(Wtl + idx8 * 8) = ol;
    }
}

// ---------------- fused feat: feat = x @ W (f16x3 MFMA), row-normalize, split hi/lo -----
// Barrier-free main loop: A = direct global f32 + in-reg split (waves don't share rows);
// B = fragment-ordered W image, coalesced global->reg. LDS only for epilogue transpose.
__global__ __launch_bounds__(256) void fused_feat(const float* __restrict__ x,
                                                  const _Float16* __restrict__ Wth,
                                                  const _Float16* __restrict__ Wtl,
                                                  _Float16* __restrict__ fhi,
                                                  _Float16* __restrict__ flo) {
    __shared__ float few[4][16][132];       // epilogue transpose only (~34 KB)

    int t = threadIdx.x;
    int w = t >> 6, lr = t & 15, lg = (t >> 4) & 3;
    int row0 = blockIdx.x * 64;
    int sIdx = blockIdx.y;

    const half8* wh = (const half8*)Wth;
    const half8* wl = (const half8*)Wtl;
    const float* xrow = x + (size_t)(row0 + w * 16 + lr) * NDIM + lg * 8;

    f32x4 c0[8], c1[8];
#pragma unroll
    for (int i = 0; i < 8; ++i) { c0[i] = (f32x4){0.f,0.f,0.f,0.f}; c1[i] = c0[i]; }

    for (int it = 0; it < 16; ++it) {
        float4 f0 = *(const float4*)(xrow + it * 32);
        float4 f1 = *(const float4*)(xrow + it * 32 + 4);
        float fv[8] = {f0.x, f0.y, f0.z, f0.w, f1.x, f1.y, f1.z, f1.w};
        half8 ah, al;
#pragma unroll
        for (int j = 0; j < 8; ++j) {
            _Float16 h = (_Float16)fv[j];
            ah[j] = h;
            al[j] = (_Float16)((fv[j] - (float)h) * 4096.0f);
        }
        size_t wb = ((size_t)(sIdx * 16 + it) * 8) * 64 + lg * 16 + lr;
#pragma unroll
        for (int set = 0; set < 8; ++set) {
            half8 bh = wh[wb + set * 64];
            half8 bl = wl[wb + set * 64];
            c0[set] = __builtin_amdgcn_mfma_f32_16x16x32_f16(ah, bh, c0[set], 0, 0, 0);
            c1[set] = __builtin_amdgcn_mfma_f32_16x16x32_f16(ah, bl, c1[set], 0, 0, 0);
            c1[set] = __builtin_amdgcn_mfma_f32_16x16x32_f16(al, bh, c1[set], 0, 0, 0);
        }
    }

    // epilogue: combine, normalize (per row over 128 cols), LDS transpose, split + store
    float ss[4] = {0.f, 0.f, 0.f, 0.f};
    float vv[8][4];
#pragma unroll
    for (int set = 0; set < 8; ++set)
#pragma unroll
        for (int r = 0; r < 4; ++r) {
            float v = fmaf(c1[set][r], SCALE_DN, c0[set][r]);
            vv[set][r] = v;
            ss[r] = fmaf(v, v, ss[r]);
        }
#pragma unroll
    for (int r = 0; r < 4; ++r) {
#pragma unroll
        for (int m = 1; m < 16; m <<= 1) ss[r] += __shfl_xor(ss[r], m);
    }
    float rn[4];
#pragma unroll
    for (int r = 0; r < 4; ++r) rn[r] = rsqrtf(ss[r]);
#pragma unroll
    for (int set = 0; set < 8; ++set)
#pragma unroll
        for (int r = 0; r < 4; ++r)
            few[w][4 * lg + r][set * 16 + lr] = vv[set][r] * rn[r];
    __syncthreads();
    int l = t & 63;
    int rr = l >> 2, q = l & 3;
    size_t btg = (size_t)(row0 + w * 16 + rr);
    size_t dst = (btg * 4 + sIdx) * DDIM + q * 32;
#pragma unroll
    for (int g = 0; g < 4; ++g) {
        half8 oh, ol;
#pragma unroll
        for (int j = 0; j < 8; ++j) {
            float f = few[w][rr][q * 32 + g * 8 + j];
            _Float16 h = (_Float16)f;
            oh[j] = h;
            ol[j] = (_Float16)((f - (float)h) * 4096.0f);
        }
        *(half8*)(fhi + dst + g * 8) = oh;
        *(half8*)(flo + dst + g * 8) = ol;
    }
}

// ---------------- sim + argmax partial: 256 feat rows x 2048-code slice -----------------
// R6 structure (verified fastest) + s_setprio around the MFMA cluster.
__global__ __launch_bounds__(256, 2) void sim_argmax_part(const _Float16* __restrict__ fhi,
                                                          const _Float16* __restrict__ flo,
                                                          const _Float16* __restrict__ chi,
                                                          const _Float16* __restrict__ clo,
                                                          float* __restrict__ pv,
                                                          int* __restrict__ pi) {
    __shared__ float redv[256][17];
    __shared__ int   redi[256][17];

    int t = threadIdx.x;
    int w = t >> 6, l = t & 63, lr = t & 15, lg = (t >> 4) & 3;
    int row0 = blockIdx.x * 256;
    int q = blockIdx.y;

    // A fragments (4 sets x 4 kt), resident whole kernel
    half8 ahi[4][4], alo[4][4];
#pragma unroll
    for (int s = 0; s < 4; ++s)
#pragma unroll
        for (int kt = 0; kt < 4; ++kt) {
            size_t off = (size_t)(row0 + w * 64 + s * 16 + lr) * DDIM + kt * 32 + lg * 8;
            ahi[s][kt] = *(const half8*)(fhi + off);
            alo[s][kt] = *(const half8*)(flo + off);
        }

    // fragment-order image: half8 index = tile*256 + kt*64 + lane
    const half8* cf = (const half8*)chi;
    const half8* cv = (const half8*)clo;
    size_t base = (size_t)(q * (NEMBED / NQ / 16)) * 256 + l;

    half8 bh[4], bl[4];
#pragma unroll
    for (int kt = 0; kt < 4; ++kt) {
        bh[kt] = cf[base + kt * 64];
        bl[kt] = cv[base + kt * 64];
    }

    float best[4][4];
    int btile[4][4];
#pragma unroll
    for (int s = 0; s < 4; ++s)
#pragma unroll
        for (int r = 0; r < 4; ++r) { best[s][r] = -1e30f; btile[s][r] = 0; }

    const int NT = NEMBED / (16 * NQ);   // 128 tiles per slice
    for (int it = 0; it < NT; ++it) {
        f32x4 a0[4], a1[4];
#pragma unroll
        for (int s = 0; s < 4; ++s) { a0[s] = (f32x4){0.f,0.f,0.f,0.f}; a1[s] = a0[s]; }
        size_t nb = base + (size_t)(it + 1) * 256;
        bool have = (it + 1) < NT;
        __builtin_amdgcn_s_setprio(1);
#pragma unroll
        for (int kt = 0; kt < 4; ++kt) {
#pragma unroll
            for (int s = 0; s < 4; ++s) {
                a0[s] = __builtin_amdgcn_mfma_f32_16x16x32_f16(ahi[s][kt], bh[kt], a0[s], 0, 0, 0);
                a1[s] = __builtin_amdgcn_mfma_f32_16x16x32_f16(ahi[s][kt], bl[kt], a1[s], 0, 0, 0);
                a1[s] = __builtin_amdgcn_mfma_f32_16x16x32_f16(alo[s][kt], bh[kt], a1[s], 0, 0, 0);
            }
            if (have) {   // WAR-safe: MFMAs above already read bh/bl at issue
                bh[kt] = cf[nb + kt * 64];
                bl[kt] = cv[nb + kt * 64];
            }
        }
        __builtin_amdgcn_s_setprio(0);
#pragma unroll
        for (int s = 0; s < 4; ++s)
#pragma unroll
            for (int r = 0; r < 4; ++r) {
                float v = fmaf(a1[s][r], SCALE_DN, a0[s][r]);
                if (v > best[s][r]) { best[s][r] = v; btile[s][r] = it; }
            }
    }

#pragma unroll
    for (int s = 0; s < 4; ++s)
#pragma unroll
        for (int r = 0; r < 4; ++r) {
            int row = w * 64 + s * 16 + 4 * lg + r;
            redv[row][lr] = best[s][r];
            redi[row][lr] = q * (NEMBED / NQ) + btile[s][r] * 16 + lr;
        }
    __syncthreads();
    {
        float bv = redv[t][0]; int bi = redi[t][0];
#pragma unroll
        for (int c = 1; c < 16; ++c) {
            float v = redv[t][c]; int ii = redi[t][c];
            if (v > bv || (v == bv && ii < bi)) { bv = v; bi = ii; }
        }
        pv[(size_t)q * ROWS + row0 + t] = bv;
        pi[(size_t)q * ROWS + row0 + t] = bi;
    }
}

// ---------------- merge NQ slice-candidates per row -------------------------------------
__global__ __launch_bounds__(256) void merge_argmax(const float* __restrict__ pv,
                                                    const int* __restrict__ pi,
                                                    int* __restrict__ out) {
    int row = blockIdx.x * 256 + threadIdx.x;
    float bv = pv[row]; int bi = pi[row];
#pragma unroll
    for (int q = 1; q < NQ; ++q) {
        float v = pv[(size_t)q * ROWS + row];
        if (v > bv) { bv = v; bi = pi[(size_t)q * ROWS + row]; }   // ties -> lower q wins
    }
    out[row] = bi;
}

extern "C" void kernel_launch(void* const* d_in, const int* in_sizes, int n_in,
                              void* d_out, int out_size, void* d_ws, size_t ws_size,
                              hipStream_t stream) {
    const float* x    = (const float*)d_in[0];   // [32,256,512]
    const float* proj = (const float*)d_in[1];   // [512,128]
    const float* cb   = (const float*)d_in[2];   // [1,8192,128]
    const int*   rm   = (const int*)d_in[3];     // [257]
    int* out = (int*)d_out;                      // [32,256,4,1] int32

    char* wsb = (char*)d_ws;
    _Float16* Wth  = (_Float16*)(wsb + 0);           // 512 KB (B-fragment order)
    _Float16* Wtl  = (_Float16*)(wsb + 524288);      // 512 KB
    _Float16* chi  = (_Float16*)(wsb + 1048576);     // 2 MB (B-fragment order)
    _Float16* clo  = (_Float16*)(wsb + 3145728);     // 2 MB
    _Float16* fhi  = (_Float16*)(wsb + 5242880);     // 8 MB
    _Float16* flo  = (_Float16*)(wsb + 13631488);    // 8 MB
    float*    pv   = (float*)(wsb + 22020096);       // 512 KB
    int*      pi   = (int*)(wsb + 22544384);         // 512 KB (end ~23 MB)

    prep_kernel<<<640, 256, 0, stream>>>(cb, proj, rm, chi, clo, Wth, Wtl);
    fused_feat<<<dim3(128, 4), 256, 0, stream>>>(x, Wth, Wtl, fhi, flo);
    sim_argmax_part<<<dim3(ROWS / 256, NQ), 256, 0, stream>>>(fhi, flo, chi, clo, pv, pi);
    merge_argmax<<<ROWS / 256, 256, 0, stream>>>(pv, pi, out);
}

// Round 11
// 284.308 us; speedup vs baseline: 1.0435x; 1.0435x over previous
//
#include <hip/hip_runtime.h>
#include <math.h>

#define BT 8192      // B*T
#define NDIM 512     // INPUT_DIM
#define NFREQ 257
#define DDIM 128     // VQ_DIM
#define NEMBED 8192
#define NQ 4         // codebook slices
#define ROWS 32768   // BT*4 splits

typedef _Float16 half8 __attribute__((ext_vector_type(8)));
typedef float f32x4 __attribute__((ext_vector_type(4)));

#define SCALE_DN 2.44140625e-4f   // 2^-12

// ---- prep: [0,512) codebook split | [512,640) W build | [640,1152) x split -------------
// cb part: normalize + f16 hi/lo split -> B-fragment-ordered image.
// W part: rebuild K_s from cos LUT, window-conv vs proj -> fragment-ordered Wth/Wtl.
// x part: one-time LDS transpose of x -> f16 hi/lo A-FRAGMENT images:
//   img half8 idx = (rt*16 + it)*64 + lg*16 + lr  holding x[rt*16+lr][it*32+lg*8 .. +8]
__global__ __launch_bounds__(256) void prep_kernel(const float* __restrict__ cb,
                                                   const float* __restrict__ proj,
                                                   const int* __restrict__ rm,
                                                   const float* __restrict__ x,
                                                   _Float16* __restrict__ chi,
                                                   _Float16* __restrict__ clo,
                                                   _Float16* __restrict__ Wth,
                                                   _Float16* __restrict__ Wtl,
                                                   _Float16* __restrict__ xhi,
                                                   _Float16* __restrict__ xlo) {
    __shared__ __align__(16) char psm[33088];
    int t = threadIdx.x;
    if (blockIdx.x < 512) {
        // ---- codebook split ----
        float (*tile)[132] = (float(*)[132])psm;
        float* rns = (float*)(psm + 16 * 132 * 4);
        int tileIdx = blockIdx.x;
        int row = t >> 4, seg = t & 15;
        const float* src = cb + ((size_t)tileIdx * 16 + row) * DDIM + seg * 8;
        float4 v0 = *(const float4*)src;
        float4 v1 = *(const float4*)(src + 4);
        *(float4*)&tile[row][seg * 8] = v0;
        *(float4*)&tile[row][seg * 8 + 4] = v1;
        float ss = v0.x * v0.x;
        ss = fmaf(v0.y, v0.y, ss); ss = fmaf(v0.z, v0.z, ss); ss = fmaf(v0.w, v0.w, ss);
        ss = fmaf(v1.x, v1.x, ss); ss = fmaf(v1.y, v1.y, ss);
        ss = fmaf(v1.z, v1.z, ss); ss = fmaf(v1.w, v1.w, ss);
#pragma unroll
        for (int m = 1; m < 16; m <<= 1) ss += __shfl_xor(ss, m);
        if (seg == 0) rns[row] = 1.0f / sqrtf(ss);
        __syncthreads();
        int cr = t & 15, lgq = (t >> 4) & 3, kt = t >> 6;
        int k0 = kt * 32 + lgq * 8;
        float rn = rns[cr];
        half8 oh, ol;
#pragma unroll
        for (int j = 0; j < 8; ++j) {
            float f = tile[cr][k0 + j] * rn;
            _Float16 h = (_Float16)f;
            oh[j] = h;
            ol[j] = (_Float16)((f - (float)h) * 4096.0f);
        }
        size_t dst = (size_t)tileIdx * 2048 + t * 8;
        *(half8*)(chi + dst) = oh;
        *(half8*)(clo + dst) = ol;
    } else if (blockIdx.x < 640) {
        // ---- W^T build + f16 split, fragment-ordered output ----
        float* ctab = (float*)psm;               // 512 f
        float* Ks   = (float*)(psm + 2048);      // 512 f
        int*   rms  = (int*)(psm + 4096);        // 257 i
        int bxp = blockIdx.x - 512;          // [0,128)
        int s = bxp & 3, ntp = bxp >> 2;     // s split, 16-k group
        int d = t & 127;
        int n0 = ntp * 16 + (t >> 7) * 8;
        for (int i = t; i < 512; i += 256) ctab[i] = cospif((float)i * (1.0f / 256.0f));
        for (int i = t; i < NFREQ; i += 256) rms[i] = rm[i];
        __syncthreads();
        for (int base = t; base < 512; base += 256) {
            float acc = 0.0f;
            for (int f = 0; f < NFREQ; ++f) {
                float w = (f == 0 || f == 256) ? 1.0f : 2.0f;
                float c = w * ctab[(f * base) & 511];
                acc += (rms[f] == s) ? c : 0.0f;
            }
            Ks[base] = acc * (1.0f / 512.0f);
        }
        __syncthreads();
        float acc[8] = {};
        for (int p16 = 0; p16 < 512; p16 += 16) {
            float wv[23];
#pragma unroll
            for (int j2 = 0; j2 < 23; ++j2) wv[j2] = Ks[(p16 - n0 + j2 - 7) & 511];
#pragma unroll
            for (int j = 0; j < 16; ++j) {
                float xp = proj[(p16 + j) * DDIM + d];
#pragma unroll
                for (int i = 0; i < 8; ++i)
                    acc[i] = fmaf(xp, wv[7 + j - i], acc[i]);
            }
        }
        int set = d >> 4, lr = d & 15;
        int itk = n0 >> 5, lg = (n0 >> 3) & 3;
        size_t idx8 = ((size_t)((s * 16 + itk) * 8 + set)) * 64 + lg * 16 + lr;
        half8 oh, ol;
#pragma unroll
        for (int i = 0; i < 8; ++i) {
            float f = acc[i] * 256.0f;      // pre-scale: dodge f16 denormals (norm cancels)
            _Float16 h = (_Float16)f;
            oh[i] = h;
            ol[i] = (_Float16)((f - (float)h) * 4096.0f);
        }
        *(half8*)(Wth + idx8 * 8) = oh;
        *(half8*)(Wtl + idx8 * 8) = ol;
    } else {
        // ---- x split -> A-fragment image (one-time coalesced transpose via LDS) ----
        float* xs = (float*)psm;                 // [16][516]
        int rt = blockIdx.x - 640;               // [0,512)
        const float* src = x + (size_t)rt * 16 * NDIM;
#pragma unroll
        for (int k2 = 0; k2 < 8; ++k2) {
            int idx = t * 4 + k2 * 1024;
            float4 v = *(const float4*)(src + idx);
            *(float4*)&xs[(idx >> 9) * 516 + (idx & 511)] = v;
        }
        __syncthreads();
#pragma unroll
        for (int k2 = 0; k2 < 4; ++k2) {
            int s = t + k2 * 256;                // [0,1024) half8 slots
            int it = s >> 6, lg = (s >> 4) & 3, lr = s & 15;
            const float* p = &xs[lr * 516 + it * 32 + lg * 8];
            half8 oh, ol;
#pragma unroll
            for (int j = 0; j < 8; ++j) {
                float f = p[j];
                _Float16 h = (_Float16)f;
                oh[j] = h;
                ol[j] = (_Float16)((f - (float)h) * 4096.0f);
            }
            size_t d8 = ((size_t)rt * 1024 + s) * 8;
            *(half8*)(xhi + d8) = oh;
            *(half8*)(xlo + d8) = ol;
        }
    }
}

// ---- fused feat: feat = x @ W (f16x3 MFMA), row-normalize, split hi/lo -----------------
// 512 threads = 8 waves x 32 rows (2 row-sets); 256 rows/block; grid (32, 4 splits).
// A from fragment images (coalesced global); W staged per-iter into LDS in fragment
// order (conflict-free ds_read_b128), reg-staged double-buffer. 48 MFMA : 16 ds_read.
__global__ __launch_bounds__(512) void fused_feat(const _Float16* __restrict__ xhi,
                                                  const _Float16* __restrict__ xlo,
                                                  const _Float16* __restrict__ Wth,
                                                  const _Float16* __restrict__ Wtl,
                                                  _Float16* __restrict__ fhi,
                                                  _Float16* __restrict__ flo) {
    __shared__ half8 Bh[2][512];                 // 16 KB
    __shared__ half8 Bl[2][512];                 // 16 KB
    __shared__ float few[8][16][132];            // 67.5 KB (epilogue)

    int t = threadIdx.x;
    int w = t >> 6, l = t & 63, lr = t & 15, lg = (t >> 4) & 3;
    int sIdx = blockIdx.y;
    int rtg0 = blockIdx.x * 16 + w * 2;          // wave's two 16-row tiles
    int rtg1 = rtg0 + 1;

    const half8* ah8 = (const half8*)xhi;
    const half8* al8 = (const half8*)xlo;
    const half8* wh8 = (const half8*)Wth;
    const half8* wl8 = (const half8*)Wtl;
    size_t wbase = (size_t)sIdx * 16 * 512;      // 512 half8 per (sIdx,it) slice

    f32x4 c0[2][8], c1[2][8];
#pragma unroll
    for (int s = 0; s < 2; ++s)
#pragma unroll
        for (int i = 0; i < 8; ++i) { c0[s][i] = (f32x4){0.f,0.f,0.f,0.f}; c1[s][i] = c0[s][i]; }

    // prologue: stage slice 0 into buf 0
    Bh[0][t] = wh8[wbase + t];
    Bl[0][t] = wl8[wbase + t];

    for (int it = 0; it < 16; ++it) {
        __syncthreads();
        int buf = it & 1;
        half8 nh, nl;
        bool have = (it + 1) < 16;
        if (have) {
            nh = wh8[wbase + (size_t)(it + 1) * 512 + t];
            nl = wl8[wbase + (size_t)(it + 1) * 512 + t];
        }
        half8 a0h = ah8[(size_t)rtg0 * 1024 + it * 64 + l];
        half8 a0l = al8[(size_t)rtg0 * 1024 + it * 64 + l];
        half8 a1h = ah8[(size_t)rtg1 * 1024 + it * 64 + l];
        half8 a1l = al8[(size_t)rtg1 * 1024 + it * 64 + l];
#pragma unroll
        for (int set = 0; set < 8; ++set) {
            half8 bh = Bh[buf][set * 64 + l];
            half8 bl = Bl[buf][set * 64 + l];
            c0[0][set] = __builtin_amdgcn_mfma_f32_16x16x32_f16(a0h, bh, c0[0][set], 0, 0, 0);
            c1[0][set] = __builtin_amdgcn_mfma_f32_16x16x32_f16(a0h, bl, c1[0][set], 0, 0, 0);
            c1[0][set] = __builtin_amdgcn_mfma_f32_16x16x32_f16(a0l, bh, c1[0][set], 0, 0, 0);
            c0[1][set] = __builtin_amdgcn_mfma_f32_16x16x32_f16(a1h, bh, c0[1][set], 0, 0, 0);
            c1[1][set] = __builtin_amdgcn_mfma_f32_16x16x32_f16(a1h, bl, c1[1][set], 0, 0, 0);
            c1[1][set] = __builtin_amdgcn_mfma_f32_16x16x32_f16(a1l, bh, c1[1][set], 0, 0, 0);
        }
        __syncthreads();
        if (have) {
            Bh[buf ^ 1][t] = nh;
            Bl[buf ^ 1][t] = nl;
        }
    }
    __syncthreads();

    // epilogue: two phases (one per row-set); combine, normalize, LDS transpose, store
#pragma unroll
    for (int srow = 0; srow < 2; ++srow) {
        float ss[4] = {0.f, 0.f, 0.f, 0.f};
        float vv[8][4];
#pragma unroll
        for (int set = 0; set < 8; ++set)
#pragma unroll
            for (int r = 0; r < 4; ++r) {
                float v = fmaf(c1[srow][set][r], SCALE_DN, c0[srow][set][r]);
                vv[set][r] = v;
                ss[r] = fmaf(v, v, ss[r]);
            }
#pragma unroll
        for (int r = 0; r < 4; ++r) {
#pragma unroll
            for (int m = 1; m < 16; m <<= 1) ss[r] += __shfl_xor(ss[r], m);
        }
        float rn[4];
#pragma unroll
        for (int r = 0; r < 4; ++r) rn[r] = rsqrtf(ss[r]);
#pragma unroll
        for (int set = 0; set < 8; ++set)
#pragma unroll
            for (int r = 0; r < 4; ++r)
                few[w][4 * lg + r][set * 16 + lr] = vv[set][r] * rn[r];
        __syncthreads();
        int rr = l >> 2, qq = l & 3;
        size_t btg = (size_t)(blockIdx.x * 256 + w * 32 + srow * 16 + rr);
        size_t dst = (btg * 4 + sIdx) * DDIM + qq * 32;
#pragma unroll
        for (int g = 0; g < 4; ++g) {
            half8 oh, ol;
#pragma unroll
            for (int j = 0; j < 8; ++j) {
                float f = few[w][rr][qq * 32 + g * 8 + j];
                _Float16 h = (_Float16)f;
                oh[j] = h;
                ol[j] = (_Float16)((f - (float)h) * 4096.0f);
            }
            *(half8*)(fhi + dst + g * 8) = oh;
            *(half8*)(flo + dst + g * 8) = ol;
        }
        __syncthreads();
    }
}

// ---- sim + argmax partial: 256 feat rows x 2048-code slice (R6 structure + setprio) ----
__global__ __launch_bounds__(256, 2) void sim_argmax_part(const _Float16* __restrict__ fhi,
                                                          const _Float16* __restrict__ flo,
                                                          const _Float16* __restrict__ chi,
                                                          const _Float16* __restrict__ clo,
                                                          float* __restrict__ pv,
                                                          int* __restrict__ pi) {
    __shared__ float redv[256][17];
    __shared__ int   redi[256][17];

    int t = threadIdx.x;
    int w = t >> 6, l = t & 63, lr = t & 15, lg = (t >> 4) & 3;
    int row0 = blockIdx.x * 256;
    int q = blockIdx.y;

    half8 ahi[4][4], alo[4][4];
#pragma unroll
    for (int s = 0; s < 4; ++s)
#pragma unroll
        for (int kt = 0; kt < 4; ++kt) {
            size_t off = (size_t)(row0 + w * 64 + s * 16 + lr) * DDIM + kt * 32 + lg * 8;
            ahi[s][kt] = *(const half8*)(fhi + off);
            alo[s][kt] = *(const half8*)(flo + off);
        }

    const half8* cf = (const half8*)chi;
    const half8* cv = (const half8*)clo;
    size_t base = (size_t)(q * (NEMBED / NQ / 16)) * 256 + l;

    half8 bh[4], bl[4];
#pragma unroll
    for (int kt = 0; kt < 4; ++kt) {
        bh[kt] = cf[base + kt * 64];
        bl[kt] = cv[base + kt * 64];
    }

    float best[4][4];
    int btile[4][4];
#pragma unroll
    for (int s = 0; s < 4; ++s)
#pragma unroll
        for (int r = 0; r < 4; ++r) { best[s][r] = -1e30f; btile[s][r] = 0; }

    const int NT = NEMBED / (16 * NQ);   // 128 tiles per slice
    for (int it = 0; it < NT; ++it) {
        f32x4 a0[4], a1[4];
#pragma unroll
        for (int s = 0; s < 4; ++s) { a0[s] = (f32x4){0.f,0.f,0.f,0.f}; a1[s] = a0[s]; }
        size_t nb = base + (size_t)(it + 1) * 256;
        bool have = (it + 1) < NT;
        __builtin_amdgcn_s_setprio(1);
#pragma unroll
        for (int kt = 0; kt < 4; ++kt) {
#pragma unroll
            for (int s = 0; s < 4; ++s) {
                a0[s] = __builtin_amdgcn_mfma_f32_16x16x32_f16(ahi[s][kt], bh[kt], a0[s], 0, 0, 0);
                a1[s] = __builtin_amdgcn_mfma_f32_16x16x32_f16(ahi[s][kt], bl[kt], a1[s], 0, 0, 0);
                a1[s] = __builtin_amdgcn_mfma_f32_16x16x32_f16(alo[s][kt], bh[kt], a1[s], 0, 0, 0);
            }
            if (have) {   // WAR-safe: MFMAs above already read bh/bl at issue
                bh[kt] = cf[nb + kt * 64];
                bl[kt] = cv[nb + kt * 64];
            }
        }
        __builtin_amdgcn_s_setprio(0);
#pragma unroll
        for (int s = 0; s < 4; ++s)
#pragma unroll
            for (int r = 0; r < 4; ++r) {
                float v = fmaf(a1[s][r], SCALE_DN, a0[s][r]);
                if (v > best[s][r]) { best[s][r] = v; btile[s][r] = it; }
            }
    }

#pragma unroll
    for (int s = 0; s < 4; ++s)
#pragma unroll
        for (int r = 0; r < 4; ++r) {
            int row = w * 64 + s * 16 + 4 * lg + r;
            redv[row][lr] = best[s][r];
            redi[row][lr] = q * (NEMBED / NQ) + btile[s][r] * 16 + lr;
        }
    __syncthreads();
    {
        float bv = redv[t][0]; int bi = redi[t][0];
#pragma unroll
        for (int c = 1; c < 16; ++c) {
            float v = redv[t][c]; int ii = redi[t][c];
            if (v > bv || (v == bv && ii < bi)) { bv = v; bi = ii; }
        }
        pv[(size_t)q * ROWS + row0 + t] = bv;
        pi[(size_t)q * ROWS + row0 + t] = bi;
    }
}

// ---- merge NQ slice-candidates per row -------------------------------------------------
__global__ __launch_bounds__(256) void merge_argmax(const float* __restrict__ pv,
                                                    const int* __restrict__ pi,
                                                    int* __restrict__ out) {
    int row = blockIdx.x * 256 + threadIdx.x;
    float bv = pv[row]; int bi = pi[row];
#pragma unroll
    for (int q = 1; q < NQ; ++q) {
        float v = pv[(size_t)q * ROWS + row];
        if (v > bv) { bv = v; bi = pi[(size_t)q * ROWS + row]; }   // ties -> lower q wins
    }
    out[row] = bi;
}

extern "C" void kernel_launch(void* const* d_in, const int* in_sizes, int n_in,
                              void* d_out, int out_size, void* d_ws, size_t ws_size,
                              hipStream_t stream) {
    const float* x    = (const float*)d_in[0];   // [32,256,512]
    const float* proj = (const float*)d_in[1];   // [512,128]
    const float* cb   = (const float*)d_in[2];   // [1,8192,128]
    const int*   rm   = (const int*)d_in[3];     // [257]
    int* out = (int*)d_out;                      // [32,256,4,1] int32

    char* wsb = (char*)d_ws;
    _Float16* Wth  = (_Float16*)(wsb + 0);           // 512 KB (B-fragment order)
    _Float16* Wtl  = (_Float16*)(wsb + 524288);      // 512 KB
    _Float16* chi  = (_Float16*)(wsb + 1048576);     // 2 MB (B-fragment order)
    _Float16* clo  = (_Float16*)(wsb + 3145728);     // 2 MB
    _Float16* fhi  = (_Float16*)(wsb + 5242880);     // 8 MB
    _Float16* flo  = (_Float16*)(wsb + 13631488);    // 8 MB
    float*    pv   = (float*)(wsb + 22020096);       // 512 KB
    int*      pi   = (int*)(wsb + 22544384);         // 512 KB
    _Float16* xhi  = (_Float16*)(wsb + 23068672);    // 8 MB (A-fragment order)
    _Float16* xlo  = (_Float16*)(wsb + 31457280);    // 8 MB (end ~38 MB)

    prep_kernel<<<1152, 256, 0, stream>>>(cb, proj, rm, x, chi, clo, Wth, Wtl, xhi, xlo);
    fused_feat<<<dim3(32, 4), 512, 0, stream>>>(xhi, xlo, Wth, Wtl, fhi, flo);
    sim_argmax_part<<<dim3(ROWS / 256, NQ), 256, 0, stream>>>(fhi, flo, chi, clo, pv, pi);
    merge_argmax<<<ROWS / 256, 256, 0, stream>>>(pv, pi, out);
}